// Round 4
// baseline (306.469 us; speedup 1.0000x reference)
//
#include <hip/hip_runtime.h>

#define NN 3072
#define FF 512
#define HH 8
#define DD 64
#define SLOPEV 0.2f
#define CH 128
#define NCH (NN/CH)

typedef __bf16  bf16x8 __attribute__((ext_vector_type(8)));
typedef short   s16x8  __attribute__((ext_vector_type(8)));
typedef float   f32x4  __attribute__((ext_vector_type(4)));
typedef unsigned long long u64;

#define MFMA16(a,b,c) __builtin_amdgcn_mfma_f32_16x16x32_bf16((a),(b),(c),0,0,0)

__device__ __forceinline__ short f2bf(float x){ __bf16 b=(__bf16)x; return __builtin_bit_cast(short,b); }
__device__ __forceinline__ float bf2f(short s){ return (float)__builtin_bit_cast(__bf16,s); }
__device__ __forceinline__ bf16x8 ldbf8(const short* p){ return __builtin_bit_cast(bf16x8, *(const s16x8*)p); }

// ---- K0a: split h (fp32) into bf16 hi/lo ----
__global__ __launch_bounds__(256) void k_split_h(const float* __restrict__ h,
    short* __restrict__ hhi, short* __restrict__ hlo){
  size_t base = ((size_t)blockIdx.x*256 + threadIdx.x)*8;
  float4 v0 = *(const float4*)(h+base);
  float4 v1 = *(const float4*)(h+base+4);
  float vv[8] = {v0.x,v0.y,v0.z,v0.w,v1.x,v1.y,v1.z,v1.w};
  s16x8 hi, lo;
  #pragma unroll
  for (int j=0;j<8;j++){ short s=f2bf(vv[j]); hi[j]=s; lo[j]=f2bf(vv[j]-bf2f(s)); }
  *(s16x8*)(hhi+base)=hi; *(s16x8*)(hlo+base)=lo;
}

// ---- K0b: W[h][f][d] -> WT[h][d][f] bf16 hi/lo, plus wa = W @ a (fp32) ----
__global__ __launch_bounds__(64) void k_wt(const float* __restrict__ W, const float* __restrict__ a,
    short* __restrict__ wthi, short* __restrict__ wtlo,
    float* __restrict__ wasrc, float* __restrict__ wadst){
  int h = blockIdx.y, f0 = blockIdx.x*8, d = threadIdx.x;   // 64 threads = 1 wave
  float asv = a[h*2*DD + d];
  float adv = a[h*2*DD + DD + d];
  s16x8 vh, vl;
  #pragma unroll
  for (int j=0;j<8;j++){
    float v = W[((size_t)h*FF + f0 + j)*DD + d];
    short s = f2bf(v); vh[j]=s; vl[j]=f2bf(v-bf2f(s));
    float ws_ = v*asv, wd_ = v*adv;
    #pragma unroll
    for (int m=1;m<64;m<<=1){ ws_ += __shfl_xor(ws_,m,64); wd_ += __shfl_xor(wd_,m,64); }
    if (d==0){ wasrc[h*FF+f0+j]=ws_; wadst[h*FF+f0+j]=wd_; }
  }
  size_t o = ((size_t)h*DD + d)*FF + f0;
  *(s16x8*)(wthi+o)=vh; *(s16x8*)(wtlo+o)=vl;
}

// ---- K0c: bit-pack adj via ballot ----
__global__ __launch_bounds__(256) void k_pack(const int* __restrict__ adj, u64* __restrict__ padj){
  int idx = blockIdx.x*256 + threadIdx.x;
  u64 b = __ballot(adj[idx] > 0);
  if ((threadIdx.x & 63) == 0) padj[idx>>6] = b;
}

// ---- K1: src/dst = h @ wa  (fully fp32 -> exact softmax logits) ----
__global__ __launch_bounds__(256) void k_srcdst(const float* __restrict__ h,
    const float* __restrict__ wasrc, const float* __restrict__ wadst,
    float* __restrict__ src, float* __restrict__ dst){
  int wid = blockIdx.x*4 + (threadIdx.x>>6);      // one wave per (h,n)
  int lane = threadIdx.x & 63;
  int hh = wid / NN, n = wid - hh*NN;
  const float* hp = h + (size_t)n*FF + lane*8;
  const float* sp = wasrc + (size_t)hh*FF + lane*8;
  const float* dp = wadst + (size_t)hh*FF + lane*8;
  float4 x0 = *(const float4*)hp, x1 = *(const float4*)(hp+4);
  float4 s0 = *(const float4*)sp, s1 = *(const float4*)(sp+4);
  float4 t0 = *(const float4*)dp, t1 = *(const float4*)(dp+4);
  float s = x0.x*s0.x + x0.y*s0.y + x0.z*s0.z + x0.w*s0.w
          + x1.x*s1.x + x1.y*s1.y + x1.z*s1.z + x1.w*s1.w;
  float t = x0.x*t0.x + x0.y*t0.y + x0.z*t0.z + x0.w*t0.w
          + x1.x*t1.x + x1.y*t1.y + x1.z*t1.z + x1.w*t1.w;
  #pragma unroll
  for (int m=1;m<64;m<<=1){ s += __shfl_xor(s,m,64); t += __shfl_xor(t,m,64); }
  if (lane==0){ src[hh*NN+n]=s; dst[hh*NN+n]=t; }
}

// ---- K2: ht = h @ W[h] via split-bf16 MFMA; store htT[h][d][n] bf16 hi/lo ----
__global__ __launch_bounds__(128) void k_ht(const short* __restrict__ hhi, const short* __restrict__ hlo,
    const short* __restrict__ wthi, const short* __restrict__ wtlo,
    short* __restrict__ hthi, short* __restrict__ htlo){
  int h = blockIdx.y, n0 = blockIdx.x*32;
  int w = threadIdx.x>>6, lane = threadIdx.x&63;
  int r15 = lane&15, g = lane>>4;
  int arow = n0 + w*16 + r15;
  f32x4 acc[4] = {{0.f,0.f,0.f,0.f},{0.f,0.f,0.f,0.f},{0.f,0.f,0.f,0.f},{0.f,0.f,0.f,0.f}};
  const short* ha = hhi + (size_t)arow*FF + g*8;
  const short* la = hlo + (size_t)arow*FF + g*8;
  for (int kk=0; kk<FF; kk+=32){
    bf16x8 ahi = ldbf8(ha+kk), alo = ldbf8(la+kk);
    #pragma unroll
    for (int c=0;c<4;c++){
      size_t bo = ((size_t)h*DD + c*16 + r15)*FF + g*8 + kk;
      bf16x8 bh = ldbf8(wthi + bo), bl = ldbf8(wtlo + bo);
      acc[c] = MFMA16(ahi,bh,acc[c]);
      acc[c] = MFMA16(ahi,bl,acc[c]);
      acc[c] = MFMA16(alo,bh,acc[c]);
    }
  }
  #pragma unroll
  for (int c=0;c<4;c++){
    #pragma unroll
    for (int r=0;r<4;r++){
      float v = acc[c][r];                        // ht[n=n0+16w+4g+r][d=c*16+r15]
      short s = f2bf(v); short sl = f2bf(v - bf2f(s));
      int n = n0 + w*16 + g*4 + r;
      size_t o = ((size_t)h*DD + c*16 + r15)*NN + n;
      hthi[o]=s; htlo[o]=sl;
    }
  }
}

// ---- K3: fused masked-softmax + att write + hp, fully coalesced, MFMA via LDS ----
// block = (head, 32 n-rows), 512 threads (8 waves), LDS 40KB -> 3 blocks/CU.
__global__ __launch_bounds__(512, 6) void k_att(const u64* __restrict__ padj,
    const float* __restrict__ src, const float* __restrict__ dst,
    const short* __restrict__ hthi, const short* __restrict__ htlo,
    float* __restrict__ dout){
  __shared__ short lhi[64][CH];   // htT hi tile, cols XOR-swizzled
  __shared__ short llo[64][CH];   // htT lo tile
  __shared__ short pt [32][CH];   // normalized p tile (bf16)
  const size_t OUTOFF = (size_t)NN*HH*DD;
  int h = blockIdx.y, n0 = blockIdx.x*32;
  int t = threadIdx.x;
  int r = t>>4, j = t&15;                         // compute layout: row r, m-slice j
  int nrow = n0 + r;
  float srcv = src[h*NN + nrow];
  const float* dsth = dst + h*NN;
  const u64* arow = padj + (size_t)nrow*(NN/64);

  // ---- sweep A: row sums (coalesced: packed adj + broadcast dst) ----
  float psum = 0.f;
  for (int c=0;c<NCH;c++){
    u64 wbits = arow[c*2 + (j>>3)];
    int sh = (j&7)*8;
    const float* dp = dsth + c*CH + j*8;
    float4 d0 = *(const float4*)dp, d1 = *(const float4*)(dp+4);
    float dj[8] = {d0.x,d0.y,d0.z,d0.w,d1.x,d1.y,d1.z,d1.w};
    #pragma unroll
    for (int e=0;e<8;e++){
      float ev = srcv + dj[e];
      ev = fmaxf(ev, SLOPEV*ev);
      float p = ((wbits >> (sh+e)) & 1ull) ? __expf(ev) : 0.f;
      psum += p;
    }
  }
  #pragma unroll
  for (int m=1;m<16;m<<=1) psum += __shfl_xor(psum, m, 64);
  float inv = (psum > 0.f) ? 1.f/psum : (1.f/(float)NN);
  bool am = !(psum > 0.f);

  // ---- sweep B: recompute p, write att, stage LDS, MFMA ----
  int lane = t&63, r15 = lane&15, g = lane>>4;
  int wv = t>>6, cblk = wv&3, nh = wv>>2;         // wave owns (d-block cblk, n-half nh)
  f32x4 acc = {0.f,0.f,0.f,0.f};
  float* attrow = dout + OUTOFF + ((size_t)(h*NN + nrow))*NN;
  int sd = t>>4;                                   // staging row 0..31
  const short* ghi0 = hthi + ((size_t)(h*DD) + sd   )*NN + j*8;
  const short* ghi1 = hthi + ((size_t)(h*DD) + sd+32)*NN + j*8;
  const short* glo0 = htlo + ((size_t)(h*DD) + sd   )*NN + j*8;
  const short* glo1 = htlo + ((size_t)(h*DD) + sd+32)*NN + j*8;
  int swz_w = (j*16) ^ ((sd&7)<<4);                // staging write byte offset in row
  char* lhB = (char*)&lhi[0][0];
  char* llB = (char*)&llo[0][0];
  char* ptB = (char*)&pt[0][0];

  for (int c=0;c<NCH;c++){
    int m0 = c*CH;
    // stage htT tile (coalesced global reads)
    s16x8 v0 = *(const s16x8*)(ghi0 + m0);
    s16x8 v1 = *(const s16x8*)(ghi1 + m0);
    s16x8 v2 = *(const s16x8*)(glo0 + m0);
    s16x8 v3 = *(const s16x8*)(glo1 + m0);
    // compute p for (r, m-slice j)
    u64 wbits = arow[c*2 + (j>>3)];
    int sh = (j&7)*8;
    const float* dp = dsth + m0 + j*8;
    float4 d0 = *(const float4*)dp, d1 = *(const float4*)(dp+4);
    float dj[8] = {d0.x,d0.y,d0.z,d0.w,d1.x,d1.y,d1.z,d1.w};
    float o[8];
    #pragma unroll
    for (int e=0;e<8;e++){
      float ev = srcv + dj[e];
      ev = fmaxf(ev, SLOPEV*ev);
      float p = ((wbits >> (sh+e)) & 1ull) ? __expf(ev) : 0.f;
      if (am) p = 1.f;
      o[e] = p * inv;
    }
    f32x4 s0 = {o[0],o[1],o[2],o[3]};
    f32x4 s1 = {o[4],o[5],o[6],o[7]};
    __builtin_nontemporal_store(s0, (f32x4*)(attrow+m0+j*8));
    __builtin_nontemporal_store(s1, (f32x4*)(attrow+m0+j*8+4));
    // LDS writes (swizzled)
    *(s16x8*)(lhB + sd*(CH*2)     + swz_w) = v0;
    *(s16x8*)(lhB + (sd+32)*(CH*2)+ swz_w) = v1;
    *(s16x8*)(llB + sd*(CH*2)     + swz_w) = v2;
    *(s16x8*)(llB + (sd+32)*(CH*2)+ swz_w) = v3;
    bf16x8 pb;
    #pragma unroll
    for (int e=0;e<8;e++) pb[e] = (__bf16)o[e];
    *(bf16x8*)(ptB + r*(CH*2) + ((j*16) ^ ((r&7)<<4))) = pb;
    __syncthreads();
    // MFMA: hpT[d=cblk*16+4g+reg][n=nh*16+r15] += htT(hi+lo) * p
    #pragma unroll
    for (int ks=0;ks<4;ks++){
      int cb = (ks*64 + g*16) ^ ((r15&7)<<4);
      bf16x8 bf = *(const bf16x8*)(ptB + (nh*16+r15)*(CH*2) + cb);
      bf16x8 ah = *(const bf16x8*)(lhB + (cblk*16+r15)*(CH*2) + cb);
      bf16x8 al = *(const bf16x8*)(llB + (cblk*16+r15)*(CH*2) + cb);
      acc = MFMA16(ah, bf, acc);
      acc = MFMA16(al, bf, acc);
    }
    __syncthreads();
  }

  // ---- epilogue: acc is already normalized (B-frag was p*inv); coalesced store ----
  int n = n0 + nh*16 + r15;
  size_t ob = (size_t)n*(HH*DD) + h*DD + cblk*16 + g*4;
  __builtin_nontemporal_store(acc, (f32x4*)(dout+ob));
}

extern "C" void kernel_launch(void* const* d_in, const int* in_sizes, int n_in,
                              void* d_out, int out_size, void* d_ws, size_t ws_size,
                              hipStream_t stream) {
  const float* h   = (const float*)d_in[0];
  const int*   adj = (const int*)d_in[1];
  const float* W   = (const float*)d_in[2];
  const float* a   = (const float*)d_in[3];
  float* out = (float*)d_out;

  // workspace carve (~15.1 MB)
  short* hhi  = (short*)d_ws;
  short* hlo  = hhi  + (size_t)NN*FF;
  short* wthi = hlo  + (size_t)NN*FF;
  short* wtlo = wthi + (size_t)HH*DD*FF;
  short* hthi = wtlo + (size_t)HH*DD*FF;
  short* htlo = hthi + (size_t)HH*DD*NN;
  float* wasrc= (float*)(htlo + (size_t)HH*DD*NN);
  float* wadst= wasrc + HH*FF;
  float* srcb = wadst + HH*FF;
  float* dstb = srcb + HH*NN;
  u64*   padj = (u64*)(dstb + HH*NN);

  k_split_h<<<dim3(NN*FF/(256*8)), 256, 0, stream>>>(h, hhi, hlo);
  k_wt     <<<dim3(FF/8, HH), 64, 0, stream>>>(W, a, wthi, wtlo, wasrc, wadst);
  k_pack   <<<dim3(NN*NN/256), 256, 0, stream>>>(adj, padj);
  k_srcdst <<<dim3(HH*NN/4), 256, 0, stream>>>(h, wasrc, wadst, srcb, dstb);
  k_ht     <<<dim3(NN/32, HH), 128, 0, stream>>>(hhi, hlo, wthi, wtlo, hthi, htlo);
  k_att    <<<dim3(NN/32, HH), 512, 0, stream>>>(padj, srcb, dstb, hthi, htlo, out);
}

// Round 5
// 161.516 us; speedup vs baseline: 1.8974x; 1.8974x over previous
//
#include <hip/hip_runtime.h>

#define NN 3072
#define FF 512
#define HH 8
#define DD 64
#define SLOPEV 0.2f
#define CH 128
#define NCH (NN/CH)

typedef __bf16  bf16x8 __attribute__((ext_vector_type(8)));
typedef __bf16  bf16x4 __attribute__((ext_vector_type(4)));
typedef short   s16x8  __attribute__((ext_vector_type(8)));
typedef float   f32x4  __attribute__((ext_vector_type(4)));
typedef unsigned long long u64;

#define MFMA16(a,b,c) __builtin_amdgcn_mfma_f32_16x16x32_bf16((a),(b),(c),0,0,0)

__device__ __forceinline__ short f2bf(float x){ __bf16 b=(__bf16)x; return __builtin_bit_cast(short,b); }
__device__ __forceinline__ float bf2f(short s){ return (float)__builtin_bit_cast(__bf16,s); }
__device__ __forceinline__ bf16x8 ldbf8(const short* p){ return __builtin_bit_cast(bf16x8, *(const s16x8*)p); }

// ---- K0a: split h (fp32) into bf16 hi/lo ----
__global__ __launch_bounds__(256) void k_split_h(const float* __restrict__ h,
    short* __restrict__ hhi, short* __restrict__ hlo){
  size_t base = ((size_t)blockIdx.x*256 + threadIdx.x)*8;
  float4 v0 = *(const float4*)(h+base);
  float4 v1 = *(const float4*)(h+base+4);
  float vv[8] = {v0.x,v0.y,v0.z,v0.w,v1.x,v1.y,v1.z,v1.w};
  s16x8 hi, lo;
  #pragma unroll
  for (int j=0;j<8;j++){ short s=f2bf(vv[j]); hi[j]=s; lo[j]=f2bf(vv[j]-bf2f(s)); }
  *(s16x8*)(hhi+base)=hi; *(s16x8*)(hlo+base)=lo;
}

// ---- K0b: W[h][f][d] -> WT[h][d][f] bf16 hi/lo, plus wa = W @ a (fp32) ----
__global__ __launch_bounds__(64) void k_wt(const float* __restrict__ W, const float* __restrict__ a,
    short* __restrict__ wthi, short* __restrict__ wtlo,
    float* __restrict__ wasrc, float* __restrict__ wadst){
  int h = blockIdx.y, f0 = blockIdx.x*8, d = threadIdx.x;   // 64 threads = 1 wave
  float asv = a[h*2*DD + d];
  float adv = a[h*2*DD + DD + d];
  s16x8 vh, vl;
  #pragma unroll
  for (int j=0;j<8;j++){
    float v = W[((size_t)h*FF + f0 + j)*DD + d];
    short s = f2bf(v); vh[j]=s; vl[j]=f2bf(v-bf2f(s));
    float ws_ = v*asv, wd_ = v*adv;
    #pragma unroll
    for (int m=1;m<64;m<<=1){ ws_ += __shfl_xor(ws_,m,64); wd_ += __shfl_xor(wd_,m,64); }
    if (d==0){ wasrc[h*FF+f0+j]=ws_; wadst[h*FF+f0+j]=wd_; }
  }
  size_t o = ((size_t)h*DD + d)*FF + f0;
  *(s16x8*)(wthi+o)=vh; *(s16x8*)(wtlo+o)=vl;
}

// ---- K0c: bit-pack adj via ballot ----
__global__ __launch_bounds__(256) void k_pack(const int* __restrict__ adj, u64* __restrict__ padj){
  int idx = blockIdx.x*256 + threadIdx.x;
  u64 b = __ballot(adj[idx] > 0);
  if ((threadIdx.x & 63) == 0) padj[idx>>6] = b;
}

// ---- K1: src/dst = h @ wa  (fully fp32 -> exact softmax logits) ----
__global__ __launch_bounds__(256) void k_srcdst(const float* __restrict__ h,
    const float* __restrict__ wasrc, const float* __restrict__ wadst,
    float* __restrict__ src, float* __restrict__ dst){
  int wid = blockIdx.x*4 + (threadIdx.x>>6);      // one wave per (h,n)
  int lane = threadIdx.x & 63;
  int hh = wid / NN, n = wid - hh*NN;
  const float* hp = h + (size_t)n*FF + lane*8;
  const float* sp = wasrc + (size_t)hh*FF + lane*8;
  const float* dp = wadst + (size_t)hh*FF + lane*8;
  float4 x0 = *(const float4*)hp, x1 = *(const float4*)(hp+4);
  float4 s0 = *(const float4*)sp, s1 = *(const float4*)(sp+4);
  float4 t0 = *(const float4*)dp, t1 = *(const float4*)(dp+4);
  float s = x0.x*s0.x + x0.y*s0.y + x0.z*s0.z + x0.w*s0.w
          + x1.x*s1.x + x1.y*s1.y + x1.z*s1.z + x1.w*s1.w;
  float t = x0.x*t0.x + x0.y*t0.y + x0.z*t0.z + x0.w*t0.w
          + x1.x*t1.x + x1.y*t1.y + x1.z*t1.z + x1.w*t1.w;
  #pragma unroll
  for (int m=1;m<64;m<<=1){ s += __shfl_xor(s,m,64); t += __shfl_xor(t,m,64); }
  if (lane==0){ src[hh*NN+n]=s; dst[hh*NN+n]=t; }
}

// ---- K2: ht = h @ W[h] via split-bf16 MFMA; store htT[h][d][n] bf16 hi/lo ----
__global__ __launch_bounds__(128) void k_ht(const short* __restrict__ hhi, const short* __restrict__ hlo,
    const short* __restrict__ wthi, const short* __restrict__ wtlo,
    short* __restrict__ hthi, short* __restrict__ htlo){
  int h = blockIdx.y, n0 = blockIdx.x*32;
  int w = threadIdx.x>>6, lane = threadIdx.x&63;
  int r15 = lane&15, g = lane>>4;
  int arow = n0 + w*16 + r15;
  f32x4 acc[4] = {{0.f,0.f,0.f,0.f},{0.f,0.f,0.f,0.f},{0.f,0.f,0.f,0.f},{0.f,0.f,0.f,0.f}};
  const short* ha = hhi + (size_t)arow*FF + g*8;
  const short* la = hlo + (size_t)arow*FF + g*8;
  for (int kk=0; kk<FF; kk+=32){
    bf16x8 ahi = ldbf8(ha+kk), alo = ldbf8(la+kk);
    #pragma unroll
    for (int c=0;c<4;c++){
      size_t bo = ((size_t)h*DD + c*16 + r15)*FF + g*8 + kk;
      bf16x8 bh = ldbf8(wthi + bo), bl = ldbf8(wtlo + bo);
      acc[c] = MFMA16(ahi,bh,acc[c]);
      acc[c] = MFMA16(ahi,bl,acc[c]);
      acc[c] = MFMA16(alo,bh,acc[c]);
    }
  }
  #pragma unroll
  for (int c=0;c<4;c++){
    #pragma unroll
    for (int r=0;r<4;r++){
      float v = acc[c][r];                        // ht[n=n0+16w+4g+r][d=c*16+r15]
      short s = f2bf(v); short sl = f2bf(v - bf2f(s));
      int n = n0 + w*16 + g*4 + r;
      size_t o = ((size_t)h*DD + c*16 + r15)*NN + n;
      hthi[o]=s; htlo[o]=sl;
    }
  }
}

// ---- K3: fused masked-softmax + att write + hp, fully coalesced, MFMA via LDS ----
// block = (head, 32 n-rows), 512 threads (8 waves), LDS 40KB.
// Thread (r=t>>4, j=t&15) owns m = {c*128 + j*4..+4} U {c*128 + 64 + j*4..+4}:
// each store instruction covers 256B contiguous per row -> full-line nt writes.
__global__ __launch_bounds__(512, 6) void k_att(const u64* __restrict__ padj,
    const float* __restrict__ src, const float* __restrict__ dst,
    const short* __restrict__ hthi, const short* __restrict__ htlo,
    float* __restrict__ dout){
  __shared__ short lhi[64][CH];   // htT hi tile, cols XOR-swizzled
  __shared__ short llo[64][CH];   // htT lo tile
  __shared__ short pt [32][CH];   // normalized p tile (bf16)
  const size_t OUTOFF = (size_t)NN*HH*DD;
  int h = blockIdx.y, n0 = blockIdx.x*32;
  int t = threadIdx.x;
  int r = t>>4, j = t&15;                         // compute layout: row r, m-slices
  int nrow = n0 + r;
  float srcv = src[h*NN + nrow];
  const float* dsth = dst + h*NN;
  const u64* arow = padj + (size_t)nrow*(NN/64);

  // ---- sweep A: row sums (coalesced: packed adj + broadcast dst) ----
  float psum = 0.f;
  for (int c=0;c<NCH;c++){
    u64 w0 = arow[c*2], w1 = arow[c*2+1];
    const float* dp = dsth + c*CH + j*4;
    float4 d0 = *(const float4*)dp, d1 = *(const float4*)(dp+64);
    float dj[8] = {d0.x,d0.y,d0.z,d0.w,d1.x,d1.y,d1.z,d1.w};
    #pragma unroll
    for (int e=0;e<8;e++){
      float ev = srcv + dj[e];
      ev = fmaxf(ev, SLOPEV*ev);
      u64 bits = (e<4) ? w0 : w1;
      float p = ((bits >> (j*4 + (e&3))) & 1ull) ? __expf(ev) : 0.f;
      psum += p;
    }
  }
  #pragma unroll
  for (int m=1;m<16;m<<=1) psum += __shfl_xor(psum, m, 64);
  float inv = (psum > 0.f) ? 1.f/psum : (1.f/(float)NN);
  bool am = !(psum > 0.f);

  // ---- sweep B: recompute p, write att, stage LDS, MFMA ----
  int lane = t&63, r15 = lane&15, g = lane>>4;
  int wv = t>>6, cblk = wv&3, nh = wv>>2;         // wave owns (d-block cblk, n-half nh)
  f32x4 acc = {0.f,0.f,0.f,0.f};
  float* attrow = dout + OUTOFF + ((size_t)(h*NN + nrow))*NN;
  int sd = t>>4;                                   // staging row 0..31
  const short* ghi0 = hthi + ((size_t)(h*DD) + sd   )*NN + j*8;
  const short* ghi1 = hthi + ((size_t)(h*DD) + sd+32)*NN + j*8;
  const short* glo0 = htlo + ((size_t)(h*DD) + sd   )*NN + j*8;
  const short* glo1 = htlo + ((size_t)(h*DD) + sd+32)*NN + j*8;
  int swz_w = (j*16) ^ ((sd&7)<<4);                // staging write byte offset in row
  int pb1o = (j*8)        ^ ((r&7)<<4);            // pt write byte offsets (8B each)
  int pb2o = (128 + j*8)  ^ ((r&7)<<4);
  char* lhB = (char*)&lhi[0][0];
  char* llB = (char*)&llo[0][0];
  char* ptB = (char*)&pt[0][0];

  for (int c=0;c<NCH;c++){
    int m0 = c*CH;
    // stage htT tile (coalesced global reads)
    s16x8 v0 = *(const s16x8*)(ghi0 + m0);
    s16x8 v1 = *(const s16x8*)(ghi1 + m0);
    s16x8 v2 = *(const s16x8*)(glo0 + m0);
    s16x8 v3 = *(const s16x8*)(glo1 + m0);
    // compute p for (r, m-slices)
    u64 w0 = arow[c*2], w1 = arow[c*2+1];
    const float* dp = dsth + m0 + j*4;
    float4 d0 = *(const float4*)dp, d1 = *(const float4*)(dp+64);
    float dj[8] = {d0.x,d0.y,d0.z,d0.w,d1.x,d1.y,d1.z,d1.w};
    float o[8];
    #pragma unroll
    for (int e=0;e<8;e++){
      float ev = srcv + dj[e];
      ev = fmaxf(ev, SLOPEV*ev);
      u64 bits = (e<4) ? w0 : w1;
      float p = ((bits >> (j*4 + (e&3))) & 1ull) ? __expf(ev) : 0.f;
      if (am) p = 1.f;
      o[e] = p * inv;
    }
    f32x4 s0 = {o[0],o[1],o[2],o[3]};
    f32x4 s1 = {o[4],o[5],o[6],o[7]};
    __builtin_nontemporal_store(s0, (f32x4*)(attrow+m0+j*4));
    __builtin_nontemporal_store(s1, (f32x4*)(attrow+m0+64+j*4));
    // LDS writes (swizzled)
    *(s16x8*)(lhB + sd*(CH*2)     + swz_w) = v0;
    *(s16x8*)(lhB + (sd+32)*(CH*2)+ swz_w) = v1;
    *(s16x8*)(llB + sd*(CH*2)     + swz_w) = v2;
    *(s16x8*)(llB + (sd+32)*(CH*2)+ swz_w) = v3;
    bf16x4 pb0, pb1;
    #pragma unroll
    for (int e=0;e<4;e++){ pb0[e] = (__bf16)o[e]; pb1[e] = (__bf16)o[e+4]; }
    *(bf16x4*)(ptB + r*(CH*2) + pb1o) = pb0;
    *(bf16x4*)(ptB + r*(CH*2) + pb2o) = pb1;
    __syncthreads();
    // MFMA: hpT[d=cblk*16+4g+reg][n=nh*16+r15] += htT(hi+lo) * p
    #pragma unroll
    for (int ks=0;ks<4;ks++){
      int cb = (ks*64 + g*16) ^ ((r15&7)<<4);
      bf16x8 bf = *(const bf16x8*)(ptB + (nh*16+r15)*(CH*2) + cb);
      bf16x8 ah = *(const bf16x8*)(lhB + (cblk*16+r15)*(CH*2) + cb);
      bf16x8 al = *(const bf16x8*)(llB + (cblk*16+r15)*(CH*2) + cb);
      acc = MFMA16(ah, bf, acc);
      acc = MFMA16(al, bf, acc);
    }
    __syncthreads();
  }

  // ---- epilogue: acc is already normalized (B-frag was p*inv); coalesced store ----
  int n = n0 + nh*16 + r15;
  size_t ob = (size_t)n*(HH*DD) + h*DD + cblk*16 + g*4;
  __builtin_nontemporal_store(acc, (f32x4*)(dout+ob));
}

extern "C" void kernel_launch(void* const* d_in, const int* in_sizes, int n_in,
                              void* d_out, int out_size, void* d_ws, size_t ws_size,
                              hipStream_t stream) {
  const float* h   = (const float*)d_in[0];
  const int*   adj = (const int*)d_in[1];
  const float* W   = (const float*)d_in[2];
  const float* a   = (const float*)d_in[3];
  float* out = (float*)d_out;

  // workspace carve (~15.1 MB)
  short* hhi  = (short*)d_ws;
  short* hlo  = hhi  + (size_t)NN*FF;
  short* wthi = hlo  + (size_t)NN*FF;
  short* wtlo = wthi + (size_t)HH*DD*FF;
  short* hthi = wtlo + (size_t)HH*DD*FF;
  short* htlo = hthi + (size_t)HH*DD*NN;
  float* wasrc= (float*)(htlo + (size_t)HH*DD*NN);
  float* wadst= wasrc + HH*FF;
  float* srcb = wadst + HH*FF;
  float* dstb = srcb + HH*NN;
  u64*   padj = (u64*)(dstb + HH*NN);

  k_split_h<<<dim3(NN*FF/(256*8)), 256, 0, stream>>>(h, hhi, hlo);
  k_wt     <<<dim3(FF/8, HH), 64, 0, stream>>>(W, a, wthi, wtlo, wasrc, wadst);
  k_pack   <<<dim3(NN*NN/256), 256, 0, stream>>>(adj, padj);
  k_srcdst <<<dim3(HH*NN/4), 256, 0, stream>>>(h, wasrc, wadst, srcb, dstb);
  k_ht     <<<dim3(NN/32, HH), 128, 0, stream>>>(hhi, hlo, wthi, wtlo, hthi, htlo);
  k_att    <<<dim3(NN/32, HH), 512, 0, stream>>>(padj, srcb, dstb, hthi, htlo, out);
}